// Round 1
// baseline (1190.596 us; speedup 1.0000x reference)
//
#include <hip/hip_runtime.h>
#include <stdint.h>

typedef unsigned long long ull;
#define BB 256

// ---------------- workspace layout (bytes) ----------------
#define O_CONV   ((size_t)0)                    // 134217728  int16 convout (max layer1: 256*32*32*256)
#define O_BITSA  ((size_t)134217728)            // 4734976    bitplanes ping
#define O_BITSB  ((size_t)139452416 - 499712)   // computed below explicitly
// (explicit constants to avoid arithmetic slips)
static const size_t OFF_CONV  = 0;
static const size_t SZ_CONV   = 134217728;      // 256*32*32*256*2
static const size_t OFF_BITSA = 134217728;      // 256*4*34*34*4 = 4734976
static const size_t OFF_BITSB = 138952704;      // 256*8*18*18*4 = 2654208
static const size_t OFF_WB    = 141606912;      // 59904 words = 239616
static const size_t OFF_S     = 141846528;      // 6*256*4 = 6144
static const size_t OFF_SS    = 141852672;      // 6*256*8 = 12288
static const size_t OFF_MEAN  = 141864960;      // 12288
static const size_t OFF_INV   = 141877248;      // 12288
static const size_t OFF_H     = 141889536;      // 256*2048*4 = 2097152
static const size_t WS_NEEDED = 143986688;

// ---------------- kernels ----------------

__global__ void zero_stats_k(int* __restrict__ S, ull* __restrict__ SS) {
  int i = blockIdx.x * blockDim.x + threadIdx.x;
  if (i < 6 * 256) { S[i] = 0; SS[i] = 0ull; }
}

// pack sign bits of w[co][ci][3][3] into out[(t*K32+k)*co + c], bit j = sign(w[c][k*32+j][t])
__global__ void pack_w_k(const float* __restrict__ w, uint32_t* __restrict__ out,
                         int co, int ci) {
  int K32 = ci >> 5;
  int total = 9 * K32 * co;
  int idx = blockIdx.x * blockDim.x + threadIdx.x;
  if (idx >= total) return;
  int c  = idx % co;
  int tk = idx / co;
  int k  = tk % K32;
  int t  = tk / K32;      // t = kh*3+kw
  uint32_t word = 0;
  const float* wc = w + (size_t)c * ci * 9 + t;
  for (int j = 0; j < 32; ++j)
    if (wc[(size_t)(k * 32 + j) * 9] >= 0.f) word |= (1u << j);
  out[idx] = word;
}

// layer 0: direct conv, ci=3, co=128, H=W=32, pad=-1. Exact integer results in f32.
__global__ void conv0_k(const float* __restrict__ x, const float* __restrict__ w0,
                        short* __restrict__ convout, int* __restrict__ Sg,
                        ull* __restrict__ SSg) {
  int b  = blockIdx.x >> 4;
  int pg = blockIdx.x & 15;         // 16 pixel-groups of 64
  int co = threadIdx.x;             // 128 threads
  float ws[27];
#pragma unroll
  for (int t = 0; t < 27; ++t) ws[t] = (w0[co * 27 + t] >= 0.f) ? 1.f : -1.f;
  const float* xb = x + (size_t)b * 3072;
  int S = 0, SSi = 0;
  for (int i = 0; i < 64; ++i) {
    int p = pg * 64 + i;
    int y = p >> 5, xx = p & 31;
    float acc = 0.f;
#pragma unroll
    for (int c = 0; c < 3; ++c)
#pragma unroll
      for (int kh = 0; kh < 3; ++kh) {
        int iy = y + kh - 1;
#pragma unroll
        for (int kw = 0; kw < 3; ++kw) {
          int ix = xx + kw - 1;
          float a = (iy >= 0 && iy < 32 && ix >= 0 && ix < 32)
                        ? xb[c * 1024 + iy * 32 + ix] : -1.f;
          acc += a * ws[(c * 3 + kh) * 3 + kw];
        }
      }
    int v = __float2int_rn(acc);
    S += v; SSi += v * v;
    convout[(size_t)(b * 1024 + p) * 128 + co] = (short)v;
  }
  atomicAdd(&Sg[co], S);
  atomicAdd(&SSg[co], (ull)(long long)SSi);
}

__global__ void finalize_k(const int* __restrict__ S, const ull* __restrict__ SS,
                           double* __restrict__ meanv, double* __restrict__ invv,
                           int co, int N) {
  int c = threadIdx.x;
  if (c >= co) return;
  double m  = (double)S[c] / (double)N;
  double e2 = (double)SS[c] / (double)N;
  double var = e2 - m * m;
  meanv[c] = m;
  invv[c]  = 1.0 / sqrt(var + 1e-5);
}

// BN sign + optional 2x2 maxpool (OR of bits) + pack into padded bitplanes
// out layout: [B][K32][Ho+2][Wo+2] words (halo = 0 == -1)
__global__ void binarize_k(const short* __restrict__ conv, int co, int H, int W, int pool,
                           uint32_t* __restrict__ out, const double* __restrict__ meanv,
                           const double* __restrict__ invv, const float* __restrict__ gamma,
                           const float* __restrict__ beta, float* __restrict__ hout) {
  int K32 = co >> 5;
  int Ho = pool ? (H >> 1) : H, Wo = pool ? (W >> 1) : W;
  int PH = Ho + 2, PW = Wo + 2;
  int total = BB * K32 * PH * PW;
  int idx = blockIdx.x * blockDim.x + threadIdx.x;
  if (idx >= total) return;
  int k  = idx % K32;
  int t1 = idx / K32;
  int px = t1 % PW; int t2 = t1 / PW;
  int py = t2 % PH; int b  = t2 / PH;
  uint32_t word = 0;
  if (py >= 1 && py <= Ho && px >= 1 && px <= Wo) {
    int oy = py - 1, ox = px - 1;
    int np = pool ? 2 : 1;
    for (int dy = 0; dy < np; ++dy)
      for (int dx = 0; dx < np; ++dx) {
        int iy = oy * np + dy, ix = ox * np + dx;
        const short* cp = conv + ((size_t)((b * H + iy) * W + ix)) * co + k * 32;
        uint32_t wb = 0;
        for (int j = 0; j < 32; ++j) {
          int c = k * 32 + j;
          double y = (double)gamma[c] * ((double)cp[j] - meanv[c]) * invv[c] + (double)beta[c];
          if (y >= 0.0) wb |= (1u << j);
        }
        word |= wb;
      }
    if (hout) {   // last layer: also emit float +-1 in NCHW for the FC
      for (int j = 0; j < 32; ++j) {
        int c = k * 32 + j;
        hout[((size_t)(b * 128 + c) * 4 + oy) * 4 + ox] = ((word >> j) & 1) ? 1.f : -1.f;
      }
    }
  }
  out[((size_t)(b * K32 + k) * PH + py) * PW + px] = word;
}

// XNOR-popcount conv. act: [B][K32][H+2][H+2] words, wb: [9][K32][co] words.
// Block: 256 threads -> 64 pixels (8x8 tile) x 64 co, 4x4 per thread.
template <int K32>
__global__ void __launch_bounds__(256) conv_xnor_k(
    const uint32_t* __restrict__ act, const uint32_t* __restrict__ wb,
    short* __restrict__ convout, int* __restrict__ Sg, ull* __restrict__ SSg,
    int co, int H, int Ktot) {
  int Hp  = H + 2;
  int T   = H >> 3;
  int cot = co >> 6;
  int TT  = T * T * cot;
  int b   = blockIdx.x / TT;
  int r   = blockIdx.x % TT;
  int ct  = r % cot;
  int tt  = r / cot;
  int ty  = tt / T, tx = tt % T;
  int co_base = ct << 6;

  __shared__ __attribute__((aligned(16))) uint32_t ldsA[K32 * 10 * 12];
  __shared__ __attribute__((aligned(16))) uint32_t ldsB[9 * K32 * 64];
  __shared__ int sS[64];
  __shared__ int sSS[64];

  int tid = threadIdx.x;
  if (tid < 64) { sS[tid] = 0; sSS[tid] = 0; }
  for (int i = tid; i < 9 * K32 * 64; i += 256) {
    int c  = i & 63;
    int tk = i >> 6;
    ldsB[i] = wb[(size_t)tk * co + co_base + c];
  }
  const uint32_t* ab = act + (size_t)b * K32 * Hp * Hp;
  for (int i = tid; i < K32 * 100; i += 256) {
    int k  = i / 100;
    int rr = i % 100;
    int yy = rr / 10, xx = rr % 10;
    ldsA[(k * 10 + yy) * 12 + xx] = ab[(size_t)(k * Hp + ty * 8 + yy) * Hp + tx * 8 + xx];
  }
  __syncthreads();

  int tc   = tid & 15;    // 4-co group
  int pgp  = tid >> 4;    // 16 pixel groups
  int yrow = pgp >> 1;
  int xg   = pgp & 1;

  int acc[4][4];
#pragma unroll
  for (int i = 0; i < 4; ++i)
#pragma unroll
    for (int j = 0; j < 4; ++j) acc[i][j] = 0;

#pragma unroll 1
  for (int k = 0; k < K32; ++k) {
#pragma unroll
    for (int kh = 0; kh < 3; ++kh) {
      int abase = (k * 10 + yrow + kh) * 12 + xg * 4;
      uint4 a0 = *(const uint4*)&ldsA[abase];
      uint2 a1 = *(const uint2*)&ldsA[abase + 4];
      uint32_t arow[6] = {a0.x, a0.y, a0.z, a0.w, a1.x, a1.y};
#pragma unroll
      for (int kw = 0; kw < 3; ++kw) {
        int t = kh * 3 + kw;
        uint4 bwv = *(const uint4*)&ldsB[(t * K32 + k) * 64 + tc * 4];
        uint32_t bwa[4] = {bwv.x, bwv.y, bwv.z, bwv.w};
#pragma unroll
        for (int pi = 0; pi < 4; ++pi) {
          uint32_t aw = arow[pi + kw];
#pragma unroll
          for (int cj = 0; cj < 4; ++cj)
            acc[pi][cj] += __popc(aw ^ bwa[cj]);
        }
      }
    }
  }

  int vS[4] = {0, 0, 0, 0}, vSS[4] = {0, 0, 0, 0};
  int gy0 = ty * 8 + yrow, gx0 = tx * 8 + xg * 4;
#pragma unroll
  for (int pi = 0; pi < 4; ++pi) {
    short4 vv;
    int v0 = Ktot - 2 * acc[pi][0];
    int v1 = Ktot - 2 * acc[pi][1];
    int v2 = Ktot - 2 * acc[pi][2];
    int v3 = Ktot - 2 * acc[pi][3];
    vS[0] += v0; vSS[0] += v0 * v0;
    vS[1] += v1; vSS[1] += v1 * v1;
    vS[2] += v2; vSS[2] += v2 * v2;
    vS[3] += v3; vSS[3] += v3 * v3;
    vv.x = (short)v0; vv.y = (short)v1; vv.z = (short)v2; vv.w = (short)v3;
    size_t obase = ((size_t)(b * H + gy0) * H + (gx0 + pi)) * co + co_base + tc * 4;
    *(short4*)&convout[obase] = vv;
  }
#pragma unroll
  for (int cj = 0; cj < 4; ++cj) {
    atomicAdd(&sS[tc * 4 + cj], vS[cj]);
    atomicAdd(&sSS[tc * 4 + cj], vSS[cj]);
  }
  __syncthreads();
  if (tid < 64) {
    atomicAdd(&Sg[co_base + tid], sS[tid]);
    atomicAdd(&SSg[co_base + tid], (ull)(long long)sSS[tid]);
  }
}

// FC: out[b][j] = sum_k h[b][k]*w[j][k] + bias[j]; h in {-1,+1}
__global__ void fc_k(const float* __restrict__ h, const float* __restrict__ fcw,
                     const float* __restrict__ fcb, float* __restrict__ out) {
  int b = blockIdx.x;
  int tid = threadIdx.x;
  int j = tid & 15;
  int chunk = tid >> 4;
  __shared__ float red[16][17];
  float acc = 0.f;
  if (j < 10) {
    const float* hp = h + (size_t)b * 2048 + chunk * 128;
    const float* wp = fcw + (size_t)j * 2048 + chunk * 128;
    for (int i = 0; i < 128; ++i) acc += hp[i] * wp[i];
  }
  red[chunk][j] = acc;
  __syncthreads();
  if (tid < 10) {
    float s = fcb[tid];
    for (int c = 0; c < 16; ++c) s += red[c][tid];
    out[b * 10 + tid] = s;
  }
}

// ---------------- launch ----------------

extern "C" void kernel_launch(void* const* d_in, const int* in_sizes, int n_in,
                              void* d_out, int out_size, void* d_ws, size_t ws_size,
                              hipStream_t stream) {
  (void)in_sizes; (void)n_in; (void)out_size;
  if (ws_size < WS_NEEDED) return;  // fail visibly rather than corrupt memory

  const float* x = (const float*)d_in[0];
  const float* w[6]; const float* g[6]; const float* bt[6];
  for (int i = 0; i < 6; ++i) {
    w[i]  = (const float*)d_in[1 + 3 * i];
    g[i]  = (const float*)d_in[2 + 3 * i];
    bt[i] = (const float*)d_in[3 + 3 * i];
  }
  const float* fcw = (const float*)d_in[19];
  const float* fcb = (const float*)d_in[20];

  char* ws = (char*)d_ws;
  short*     convout = (short*)(ws + OFF_CONV);
  uint32_t*  bitsA   = (uint32_t*)(ws + OFF_BITSA);
  uint32_t*  bitsB   = (uint32_t*)(ws + OFF_BITSB);
  uint32_t*  wbits   = (uint32_t*)(ws + OFF_WB);
  int*       Sg      = (int*)(ws + OFF_S);
  ull*       SSg     = (ull*)(ws + OFF_SS);
  double*    meanv   = (double*)(ws + OFF_MEAN);
  double*    invv    = (double*)(ws + OFF_INV);
  float*     hbuf    = (float*)(ws + OFF_H);
  float*     out     = (float*)d_out;

  zero_stats_k<<<6, 256, 0, stream>>>(Sg, SSg);

  pack_w_k<<<(9 * 4 * 256 + 255) / 256, 256, 0, stream>>>(w[1], wbits + 0,     256, 128);
  pack_w_k<<<(9 * 8 * 256 + 255) / 256, 256, 0, stream>>>(w[2], wbits + 9216,  256, 256);
  pack_w_k<<<(9 * 8 * 256 + 255) / 256, 256, 0, stream>>>(w[3], wbits + 27648, 256, 256);
  pack_w_k<<<(9 * 8 * 128 + 255) / 256, 256, 0, stream>>>(w[4], wbits + 46080, 128, 256);
  pack_w_k<<<(9 * 4 * 128 + 255) / 256, 256, 0, stream>>>(w[5], wbits + 55296, 128, 128);

  // L0: ci=3 co=128 H=32, no pool
  conv0_k<<<256 * 16, 128, 0, stream>>>(x, w[0], convout, Sg, SSg);
  finalize_k<<<1, 256, 0, stream>>>(Sg, SSg, meanv, invv, 128, 262144);
  binarize_k<<<(256 * 4 * 34 * 34 + 255) / 256, 256, 0, stream>>>(
      convout, 128, 32, 32, 0, bitsA, meanv, invv, g[0], bt[0], nullptr);

  // L1: ci=128 co=256 H=32, pool
  conv_xnor_k<4><<<256 * 16 * 4, 256, 0, stream>>>(bitsA, wbits + 0, convout,
                                                   Sg + 256, SSg + 256, 256, 32, 1152);
  finalize_k<<<1, 256, 0, stream>>>(Sg + 256, SSg + 256, meanv + 256, invv + 256, 256, 262144);
  binarize_k<<<(256 * 8 * 18 * 18 + 255) / 256, 256, 0, stream>>>(
      convout, 256, 32, 32, 1, bitsB, meanv + 256, invv + 256, g[1], bt[1], nullptr);

  // L2: ci=256 co=256 H=16, no pool
  conv_xnor_k<8><<<256 * 4 * 4, 256, 0, stream>>>(bitsB, wbits + 9216, convout,
                                                  Sg + 512, SSg + 512, 256, 16, 2304);
  finalize_k<<<1, 256, 0, stream>>>(Sg + 512, SSg + 512, meanv + 512, invv + 512, 256, 65536);
  binarize_k<<<(256 * 8 * 18 * 18 + 255) / 256, 256, 0, stream>>>(
      convout, 256, 16, 16, 0, bitsA, meanv + 512, invv + 512, g[2], bt[2], nullptr);

  // L3: ci=256 co=256 H=16, pool
  conv_xnor_k<8><<<256 * 4 * 4, 256, 0, stream>>>(bitsA, wbits + 27648, convout,
                                                  Sg + 768, SSg + 768, 256, 16, 2304);
  finalize_k<<<1, 256, 0, stream>>>(Sg + 768, SSg + 768, meanv + 768, invv + 768, 256, 65536);
  binarize_k<<<(256 * 8 * 10 * 10 + 255) / 256, 256, 0, stream>>>(
      convout, 256, 16, 16, 1, bitsB, meanv + 768, invv + 768, g[3], bt[3], nullptr);

  // L4: ci=256 co=128 H=8, no pool
  conv_xnor_k<8><<<256 * 1 * 2, 256, 0, stream>>>(bitsB, wbits + 46080, convout,
                                                  Sg + 1024, SSg + 1024, 128, 8, 2304);
  finalize_k<<<1, 256, 0, stream>>>(Sg + 1024, SSg + 1024, meanv + 1024, invv + 1024, 128, 16384);
  binarize_k<<<(256 * 4 * 10 * 10 + 255) / 256, 256, 0, stream>>>(
      convout, 128, 8, 8, 0, bitsA, meanv + 1024, invv + 1024, g[4], bt[4], nullptr);

  // L5: ci=128 co=128 H=8, pool -> 4x4, also emit float h for FC
  conv_xnor_k<4><<<256 * 1 * 2, 256, 0, stream>>>(bitsA, wbits + 55296, convout,
                                                  Sg + 1280, SSg + 1280, 128, 8, 1152);
  finalize_k<<<1, 256, 0, stream>>>(Sg + 1280, SSg + 1280, meanv + 1280, invv + 1280, 128, 16384);
  binarize_k<<<(256 * 4 * 6 * 6 + 255) / 256, 256, 0, stream>>>(
      convout, 128, 8, 8, 1, bitsB, meanv + 1280, invv + 1280, g[5], bt[5], hbuf);

  fc_k<<<256, 256, 0, stream>>>(hbuf, fcw, fcb, out);
}

// Round 2
// 575.758 us; speedup vs baseline: 2.0679x; 2.0679x over previous
//
#include <hip/hip_runtime.h>
#include <stdint.h>

typedef unsigned long long ull;
#define BB 256

// ---------------- workspace layout (bytes) ----------------
static const size_t OFF_CONV  = 0;
static const size_t SZ_CONV   = 134217728;      // 256*32*32*256*2
static const size_t OFF_BITSA = 134217728;      // 256*4*34*34*4 = 4734976
static const size_t OFF_BITSB = 138952704;      // 256*8*18*18*4 = 2654208
static const size_t OFF_WB    = 141606912;      // 59904 words = 239616
static const size_t OFF_S     = 141846528;      // 6*256*4 = 6144
static const size_t OFF_SS    = 141852672;      // 6*256*8 = 12288
static const size_t OFF_ATHR  = 141864960;      // 6*256*4 (reuse old mean slot)
static const size_t OFF_BTHR  = 141877248;      // 6*256*4 (reuse old inv slot)
static const size_t OFF_H     = 141889536;      // 256*2048*4 = 2097152
static const size_t WS_NEEDED = 143986688;
// xbits lives in the UNUSED upper half of the conv buffer during layer 0
// (layer 0 conv output occupies only 256*1024*128*2 = 67,108,864 bytes)
static const size_t OFF_XBITS = 100 * 1024 * 1024;  // inside conv region, dead after L0

// ---------------- kernels ----------------

__global__ void zero_stats_k(int* __restrict__ S, ull* __restrict__ SS) {
  int i = blockIdx.x * blockDim.x + threadIdx.x;
  if (i < 6 * 256) { S[i] = 0; SS[i] = 0ull; }
}

// pack sign bits of w[co][ci][3][3] into out[(t*K32+k)*co + c], bit j = sign(w[c][k*32+j][t])
__global__ void pack_w_k(const float* __restrict__ w, uint32_t* __restrict__ out,
                         int co, int ci) {
  int K32 = ci >> 5;
  int total = 9 * K32 * co;
  int idx = blockIdx.x * blockDim.x + threadIdx.x;
  if (idx >= total) return;
  int c  = idx % co;
  int tk = idx / co;
  int k  = tk % K32;
  int t  = tk / K32;      // t = kh*3+kw
  uint32_t word = 0;
  const float* wc = w + (size_t)c * ci * 9 + t;
  for (int j = 0; j < 32; ++j)
    if (wc[(size_t)(k * 32 + j) * 9] >= 0.f) word |= (1u << j);
  out[idx] = word;
}

// pack input x (+-1) into bitplane rows: xbits[(b*3+c)*32+y], bit xx = (x>=0)
__global__ void pack_x_k(const float* __restrict__ x, uint32_t* __restrict__ xbits) {
  int idx = blockIdx.x * 256 + threadIdx.x;   // < 256*3*32 = 24576
  if (idx >= 24576) return;
  const float* xp = x + (size_t)idx * 32;
  uint32_t w = 0;
#pragma unroll
  for (int j = 0; j < 32; ++j) if (xp[j] >= 0.f) w |= (1u << j);
  xbits[idx] = w;
}

// pack w0[co][3][3][3] (co=128, ci=3) into 27-bit words, bit t=c*9+kh*3+kw
__global__ void pack_w0_k(const float* __restrict__ w0, uint32_t* __restrict__ w27) {
  int co = threadIdx.x;  // 128
  uint32_t w = 0;
#pragma unroll
  for (int t = 0; t < 27; ++t) if (w0[co * 27 + t] >= 0.f) w |= (1u << t);
  w27[co] = w;
}

// layer 0 conv via 27-bit popcount. Block: (batch b, row-group rg of 8 rows).
// 256 threads: phase1 builds 256 a27 words; phase2: thread (co=tid&127, half) does 128 pixels.
__global__ void __launch_bounds__(256) conv0x_k(
    const uint32_t* __restrict__ xbits, const uint32_t* __restrict__ w27,
    short* __restrict__ convout, int* __restrict__ Sg, ull* __restrict__ SSg) {
  int b  = blockIdx.x >> 2;
  int rg = blockIdx.x & 3;
  __shared__ uint32_t a27s[256];
  __shared__ uint32_t wlds[128];
  __shared__ int sS[256], sSS[256];
  int tid = threadIdx.x;
  if (tid < 128) wlds[tid] = w27[tid];

  int p = rg * 256 + tid;
  int y = p >> 5, xx = p & 31;
  const uint32_t* xb = xbits + (size_t)b * 96;
  uint32_t a27 = 0;
#pragma unroll
  for (int c = 0; c < 3; ++c)
#pragma unroll
    for (int kh = 0; kh < 3; ++kh) {
      int iy = y + kh - 1;
      uint32_t r = (iy >= 0 && iy < 32) ? xb[c * 32 + iy] : 0u;
      uint32_t bits3 = (uint32_t)((((uint64_t)r) << 1) >> xx) & 7u;
      a27 |= bits3 << (c * 9 + kh * 3);
    }
  a27s[tid] = a27;
  __syncthreads();

  int co = tid & 127, half = tid >> 7;
  uint32_t wv = wlds[co];
  int S = 0, SS = 0;
  int base = rg * 256 + half * 128;
  short* cb = convout + ((size_t)b * 1024 + base) * 128 + co;
  for (int i = 0; i < 128; ++i) {
    uint32_t a = a27s[half * 128 + i];
    int v = 27 - 2 * __popc(a ^ wv);
    S += v; SS += v * v;
    cb[(size_t)i * 128] = (short)v;
  }
  sS[tid] = S; sSS[tid] = SS;
  __syncthreads();
  if (tid < 128) {
    atomicAdd(&Sg[tid], sS[tid] + sS[tid + 128]);
    atomicAdd(&SSg[tid], (ull)(long long)(sSS[tid] + sSS[tid + 128]));
  }
}

// per-channel integer threshold: bit = (A*v >= B)
// gamma>0: v >= ceil(t);  gamma<0: v <= floor(t) (encoded -v >= -floor(t));  gamma==0: const
__global__ void finalize_k(const int* __restrict__ S, const ull* __restrict__ SS,
                           int* __restrict__ A, int* __restrict__ B,
                           const float* __restrict__ gamma, const float* __restrict__ beta,
                           int co, int N) {
  int c = threadIdx.x;
  if (c >= co) return;
  double m  = (double)S[c] / (double)N;
  double e2 = (double)SS[c] / (double)N;
  double inv = 1.0 / sqrt(e2 - m * m + 1e-5);
  float gg = gamma[c], bb = beta[c];
  int Ai, Bi;
  if (gg > 0.f) {
    double t = m - (double)bb / ((double)gg * inv);
    t = fmin(fmax(t, -1e6), 1e6);
    Ai = 1;  Bi = (int)ceil(t);
  } else if (gg < 0.f) {
    double t = m - (double)bb / ((double)gg * inv);
    t = fmin(fmax(t, -1e6), 1e6);
    Ai = -1; Bi = -(int)floor(t);
  } else {
    Ai = 0;  Bi = (bb >= 0.f) ? 0 : 1;
  }
  A[c] = Ai; B[c] = Bi;
}

// BN sign (integer threshold) + optional 2x2 maxpool (OR of bits) + pack into padded bitplanes
// out layout: [B][K32][Ho+2][Wo+2] words (halo = 0 == -1)
__global__ void binarize_k(const short* __restrict__ conv, int co, int H, int W, int pool,
                           uint32_t* __restrict__ out, const int* __restrict__ A,
                           const int* __restrict__ B, float* __restrict__ hout) {
  __shared__ int As[256], Bs[256];
  int tid = threadIdx.x;
  for (int i = tid; i < co; i += 256) { As[i] = A[i]; Bs[i] = B[i]; }
  __syncthreads();

  int K32 = co >> 5;
  int Ho = pool ? (H >> 1) : H, Wo = pool ? (W >> 1) : W;
  int PH = Ho + 2, PW = Wo + 2;
  int total = BB * K32 * PH * PW;
  int idx = blockIdx.x * 256 + tid;
  if (idx >= total) return;
  int k  = idx % K32;
  int t1 = idx / K32;
  int px = t1 % PW; int t2 = t1 / PW;
  int py = t2 % PH; int b  = t2 / PH;
  uint32_t word = 0;
  if (py >= 1 && py <= Ho && px >= 1 && px <= Wo) {
    int oy = py - 1, ox = px - 1;
    int np = pool ? 2 : 1;
    for (int dy = 0; dy < np; ++dy)
      for (int dx = 0; dx < np; ++dx) {
        int iy = oy * np + dy, ix = ox * np + dx;
        const short* cp = conv + ((size_t)((b * H + iy) * W + ix)) * co + k * 32;
#pragma unroll
        for (int j = 0; j < 32; ++j) {
          int v = cp[j];
          int c = k * 32 + j;
          if (As[c] * v >= Bs[c]) word |= (1u << j);
        }
      }
    if (hout) {   // last layer: emit float +-1 in NCHW for the FC
#pragma unroll
      for (int j = 0; j < 32; ++j) {
        int c = k * 32 + j;
        hout[((size_t)(b * 128 + c) * 4 + oy) * 4 + ox] = ((word >> j) & 1) ? 1.f : -1.f;
      }
    }
  }
  out[((size_t)(b * K32 + k) * PH + py) * PW + px] = word;
}

// XNOR-popcount conv. act: [B][K32][H+2][H+2] words, wb: [9][K32][co] words.
// Block: 256 threads -> 64 pixels (8x8 tile) x 64 co, 4x4 per thread.
template <int K32>
__global__ void __launch_bounds__(256) conv_xnor_k(
    const uint32_t* __restrict__ act, const uint32_t* __restrict__ wb,
    short* __restrict__ convout, int* __restrict__ Sg, ull* __restrict__ SSg,
    int co, int H, int Ktot) {
  int Hp  = H + 2;
  int T   = H >> 3;
  int cot = co >> 6;
  int TT  = T * T * cot;
  int b   = blockIdx.x / TT;
  int r   = blockIdx.x % TT;
  int ct  = r % cot;
  int tt  = r / cot;
  int ty  = tt / T, tx = tt % T;
  int co_base = ct << 6;

  __shared__ __attribute__((aligned(16))) uint32_t ldsA[K32 * 10 * 12];
  __shared__ __attribute__((aligned(16))) uint32_t ldsB[9 * K32 * 64];
  __shared__ int sS[64];
  __shared__ int sSS[64];

  int tid = threadIdx.x;
  if (tid < 64) { sS[tid] = 0; sSS[tid] = 0; }
  for (int i = tid; i < 9 * K32 * 64; i += 256) {
    int c  = i & 63;
    int tk = i >> 6;
    ldsB[i] = wb[(size_t)tk * co + co_base + c];
  }
  const uint32_t* ab = act + (size_t)b * K32 * Hp * Hp;
  for (int i = tid; i < K32 * 100; i += 256) {
    int k  = i / 100;
    int rr = i % 100;
    int yy = rr / 10, xx = rr % 10;
    ldsA[(k * 10 + yy) * 12 + xx] = ab[(size_t)(k * Hp + ty * 8 + yy) * Hp + tx * 8 + xx];
  }
  __syncthreads();

  int tc   = tid & 15;    // 4-co group
  int pgp  = tid >> 4;    // 16 pixel groups
  int yrow = pgp >> 1;
  int xg   = pgp & 1;

  int acc[4][4];
#pragma unroll
  for (int i = 0; i < 4; ++i)
#pragma unroll
    for (int j = 0; j < 4; ++j) acc[i][j] = 0;

#pragma unroll 1
  for (int k = 0; k < K32; ++k) {
#pragma unroll
    for (int kh = 0; kh < 3; ++kh) {
      int abase = (k * 10 + yrow + kh) * 12 + xg * 4;
      uint4 a0 = *(const uint4*)&ldsA[abase];
      uint2 a1 = *(const uint2*)&ldsA[abase + 4];
      uint32_t arow[6] = {a0.x, a0.y, a0.z, a0.w, a1.x, a1.y};
#pragma unroll
      for (int kw = 0; kw < 3; ++kw) {
        int t = kh * 3 + kw;
        uint4 bwv = *(const uint4*)&ldsB[(t * K32 + k) * 64 + tc * 4];
        uint32_t bwa[4] = {bwv.x, bwv.y, bwv.z, bwv.w};
#pragma unroll
        for (int pi = 0; pi < 4; ++pi) {
          uint32_t aw = arow[pi + kw];
#pragma unroll
          for (int cj = 0; cj < 4; ++cj)
            acc[pi][cj] += __popc(aw ^ bwa[cj]);
        }
      }
    }
  }

  int vS[4] = {0, 0, 0, 0}, vSS[4] = {0, 0, 0, 0};
  int gy0 = ty * 8 + yrow, gx0 = tx * 8 + xg * 4;
#pragma unroll
  for (int pi = 0; pi < 4; ++pi) {
    short4 vv;
    int v0 = Ktot - 2 * acc[pi][0];
    int v1 = Ktot - 2 * acc[pi][1];
    int v2 = Ktot - 2 * acc[pi][2];
    int v3 = Ktot - 2 * acc[pi][3];
    vS[0] += v0; vSS[0] += v0 * v0;
    vS[1] += v1; vSS[1] += v1 * v1;
    vS[2] += v2; vSS[2] += v2 * v2;
    vS[3] += v3; vSS[3] += v3 * v3;
    vv.x = (short)v0; vv.y = (short)v1; vv.z = (short)v2; vv.w = (short)v3;
    size_t obase = ((size_t)(b * H + gy0) * H + (gx0 + pi)) * co + co_base + tc * 4;
    *(short4*)&convout[obase] = vv;
  }
#pragma unroll
  for (int cj = 0; cj < 4; ++cj) {
    atomicAdd(&sS[tc * 4 + cj], vS[cj]);
    atomicAdd(&sSS[tc * 4 + cj], vSS[cj]);
  }
  __syncthreads();
  if (tid < 64) {
    atomicAdd(&Sg[co_base + tid], sS[tid]);
    atomicAdd(&SSg[co_base + tid], (ull)(long long)sSS[tid]);
  }
}

// FC: out[b][j] = sum_k h[b][k]*w[j][k] + bias[j]; h in {-1,+1}
__global__ void fc_k(const float* __restrict__ h, const float* __restrict__ fcw,
                     const float* __restrict__ fcb, float* __restrict__ out) {
  int b = blockIdx.x;
  int tid = threadIdx.x;
  int j = tid & 15;
  int chunk = tid >> 4;
  __shared__ float red[16][17];
  float acc = 0.f;
  if (j < 10) {
    const float* hp = h + (size_t)b * 2048 + chunk * 128;
    const float* wp = fcw + (size_t)j * 2048 + chunk * 128;
    for (int i = 0; i < 128; ++i) acc += hp[i] * wp[i];
  }
  red[chunk][j] = acc;
  __syncthreads();
  if (tid < 10) {
    float s = fcb[tid];
    for (int c = 0; c < 16; ++c) s += red[c][tid];
    out[b * 10 + tid] = s;
  }
}

// ---------------- launch ----------------

extern "C" void kernel_launch(void* const* d_in, const int* in_sizes, int n_in,
                              void* d_out, int out_size, void* d_ws, size_t ws_size,
                              hipStream_t stream) {
  (void)in_sizes; (void)n_in; (void)out_size;
  if (ws_size < WS_NEEDED) return;  // fail visibly rather than corrupt memory

  const float* x = (const float*)d_in[0];
  const float* w[6]; const float* g[6]; const float* bt[6];
  for (int i = 0; i < 6; ++i) {
    w[i]  = (const float*)d_in[1 + 3 * i];
    g[i]  = (const float*)d_in[2 + 3 * i];
    bt[i] = (const float*)d_in[3 + 3 * i];
  }
  const float* fcw = (const float*)d_in[19];
  const float* fcb = (const float*)d_in[20];

  char* ws = (char*)d_ws;
  short*     convout = (short*)(ws + OFF_CONV);
  uint32_t*  bitsA   = (uint32_t*)(ws + OFF_BITSA);
  uint32_t*  bitsB   = (uint32_t*)(ws + OFF_BITSB);
  uint32_t*  wbits   = (uint32_t*)(ws + OFF_WB);
  int*       Sg      = (int*)(ws + OFF_S);
  ull*       SSg     = (ull*)(ws + OFF_SS);
  int*       Athr    = (int*)(ws + OFF_ATHR);
  int*       Bthr    = (int*)(ws + OFF_BTHR);
  float*     hbuf    = (float*)(ws + OFF_H);
  uint32_t*  xbits   = (uint32_t*)(ws + OFF_XBITS);
  uint32_t*  w27     = xbits + 24576;
  float*     out     = (float*)d_out;

  zero_stats_k<<<6, 256, 0, stream>>>(Sg, SSg);

  pack_w_k<<<(9 * 4 * 256 + 255) / 256, 256, 0, stream>>>(w[1], wbits + 0,     256, 128);
  pack_w_k<<<(9 * 8 * 256 + 255) / 256, 256, 0, stream>>>(w[2], wbits + 9216,  256, 256);
  pack_w_k<<<(9 * 8 * 256 + 255) / 256, 256, 0, stream>>>(w[3], wbits + 27648, 256, 256);
  pack_w_k<<<(9 * 8 * 128 + 255) / 256, 256, 0, stream>>>(w[4], wbits + 46080, 128, 256);
  pack_w_k<<<(9 * 4 * 128 + 255) / 256, 256, 0, stream>>>(w[5], wbits + 55296, 128, 128);
  pack_x_k<<<96, 256, 0, stream>>>(x, xbits);
  pack_w0_k<<<1, 128, 0, stream>>>(w[0], w27);

  // L0: ci=3 co=128 H=32, no pool
  conv0x_k<<<256 * 4, 256, 0, stream>>>(xbits, w27, convout, Sg, SSg);
  finalize_k<<<1, 256, 0, stream>>>(Sg, SSg, Athr, Bthr, g[0], bt[0], 128, 262144);
  binarize_k<<<(256 * 4 * 34 * 34 + 255) / 256, 256, 0, stream>>>(
      convout, 128, 32, 32, 0, bitsA, Athr, Bthr, nullptr);

  // L1: ci=128 co=256 H=32, pool
  conv_xnor_k<4><<<256 * 16 * 4, 256, 0, stream>>>(bitsA, wbits + 0, convout,
                                                   Sg + 256, SSg + 256, 256, 32, 1152);
  finalize_k<<<1, 256, 0, stream>>>(Sg + 256, SSg + 256, Athr + 256, Bthr + 256, g[1], bt[1], 256, 262144);
  binarize_k<<<(256 * 8 * 18 * 18 + 255) / 256, 256, 0, stream>>>(
      convout, 256, 32, 32, 1, bitsB, Athr + 256, Bthr + 256, nullptr);

  // L2: ci=256 co=256 H=16, no pool
  conv_xnor_k<8><<<256 * 4 * 4, 256, 0, stream>>>(bitsB, wbits + 9216, convout,
                                                  Sg + 512, SSg + 512, 256, 16, 2304);
  finalize_k<<<1, 256, 0, stream>>>(Sg + 512, SSg + 512, Athr + 512, Bthr + 512, g[2], bt[2], 256, 65536);
  binarize_k<<<(256 * 8 * 18 * 18 + 255) / 256, 256, 0, stream>>>(
      convout, 256, 16, 16, 0, bitsA, Athr + 512, Bthr + 512, nullptr);

  // L3: ci=256 co=256 H=16, pool
  conv_xnor_k<8><<<256 * 4 * 4, 256, 0, stream>>>(bitsA, wbits + 27648, convout,
                                                  Sg + 768, SSg + 768, 256, 16, 2304);
  finalize_k<<<1, 256, 0, stream>>>(Sg + 768, SSg + 768, Athr + 768, Bthr + 768, g[3], bt[3], 256, 65536);
  binarize_k<<<(256 * 8 * 10 * 10 + 255) / 256, 256, 0, stream>>>(
      convout, 256, 16, 16, 1, bitsB, Athr + 768, Bthr + 768, nullptr);

  // L4: ci=256 co=128 H=8, no pool
  conv_xnor_k<8><<<256 * 1 * 2, 256, 0, stream>>>(bitsB, wbits + 46080, convout,
                                                  Sg + 1024, SSg + 1024, 128, 8, 2304);
  finalize_k<<<1, 256, 0, stream>>>(Sg + 1024, SSg + 1024, Athr + 1024, Bthr + 1024, g[4], bt[4], 128, 16384);
  binarize_k<<<(256 * 4 * 10 * 10 + 255) / 256, 256, 0, stream>>>(
      convout, 128, 8, 8, 0, bitsA, Athr + 1024, Bthr + 1024, nullptr);

  // L5: ci=128 co=128 H=8, pool -> 4x4, also emit float h for FC
  conv_xnor_k<4><<<256 * 1 * 2, 256, 0, stream>>>(bitsA, wbits + 55296, convout,
                                                  Sg + 1280, SSg + 1280, 128, 8, 1152);
  finalize_k<<<1, 256, 0, stream>>>(Sg + 1280, SSg + 1280, Athr + 1280, Bthr + 1280, g[5], bt[5], 128, 16384);
  binarize_k<<<(256 * 4 * 6 * 6 + 255) / 256, 256, 0, stream>>>(
      convout, 128, 8, 8, 1, bitsB, Athr + 1280, Bthr + 1280, hbuf);

  fc_k<<<256, 256, 0, stream>>>(hbuf, fcw, fcb, out);
}